// Round 6
// baseline (1086.777 us; speedup 1.0000x reference)
//
#include <hip/hip_runtime.h>
#include <hip/hip_bf16.h>
#include <stdint.h>

typedef unsigned short u16;
typedef unsigned int u32;

#define F1 274625   // 65^3
#define IJ1 4225    // 65^2
#define NSK 48      // split-K segments

typedef float v4f __attribute__((ext_vector_type(4)));
typedef __bf16 v8bf __attribute__((ext_vector_type(8)));

__device__ __forceinline__ float lof(u32 u) { union { u32 u; float f; } c; c.u = u << 16; return c.f; }
__device__ __forceinline__ u16 f2bf(float f) {
  union { float f; u32 u; } c; c.f = f;
  u32 r = (c.u >> 16) & 1u;
  return (u16)((c.u + 0x7fffu + r) >> 16);
}
__device__ __forceinline__ u32 pkbf(u32 a, u32 b) {
  union { float f; u32 u; } ca, cb; ca.u = a; cb.u = b;
  __hip_bfloat162 h = __float22bfloat162_rn(make_float2(ca.f, cb.f));
  union { __hip_bfloat162 h; u32 u; } c; c.h = h; return c.u;
}

// ---------------- K0: transpose vec1/2/3 [512][64] f32 -> xT [3][64][512] f32
__global__ void __launch_bounds__(256) k0_transpose(const float* __restrict__ v1,
    const float* __restrict__ v2, const float* __restrict__ v3, float* __restrict__ xT) {
  int g = blockIdx.x * 256 + threadIdx.x;
  if (g >= 3 * 64 * 512) return;
  int t = g >> 15, r = g & 32767;
  int d = r >> 9, b = r & 511;
  const float* v = (t == 0) ? v1 : ((t == 1) ? v2 : v3);
  xT[g] = v[b * 64 + d];
}

// ---------------- K3T: w2 [256][451] -> w2T [451][256] (LDS-tiled)
__global__ void __launch_bounds__(256) k3t_w2t(const float* __restrict__ w2,
                                               float* __restrict__ w2T) {
  __shared__ float t[32][33];
  int bx = blockIdx.x & 7, by = blockIdx.x >> 3;   // 8 o-tiles x 15 c-tiles
  int tx = threadIdx.x & 31, ty = threadIdx.x >> 5; // ty 0..7
  int c = by * 32 + tx;
#pragma unroll
  for (int r = 0; r < 32; r += 8) {
    int o = bx * 32 + ty + r;
    t[ty + r][tx] = (c < 451) ? w2[o * 451 + c] : 0.f;
  }
  __syncthreads();
#pragma unroll
  for (int r = 0; r < 32; r += 8) {
    int cc = by * 32 + ty + r;
    if (cc < 451) w2T[cc * 256 + bx * 32 + tx] = t[tx][ty + r];
  }
}

// ---------------- K1: bilinear -> zsum [3][64][512] f32; weights staged in LDS
// z_t[b,o] = sum_i x1[b,i] * sum_j zw_t[o,i,j] * vec3[b,j]
__global__ void __launch_bounds__(256) k1_bilinear(
    const float* __restrict__ zw1, const float* __restrict__ zw2, const float* __restrict__ zw3,
    const float* __restrict__ xT, float* __restrict__ zsum) {
  __shared__ float wsm[4096];
  int bid = blockIdx.x;                 // 384 = t*128 + o*2 + bh
  int bh = bid & 1, o = (bid >> 1) & 63, t = bid >> 7;
  int tid = threadIdx.x;
  const float* zw = (t == 0) ? zw1 : ((t == 1) ? zw2 : zw3);
  {  // stage zw[o,:,:] 4096 f32, coalesced
    const float4* src = (const float4*)(zw + o * 4096);
    float4* dst = (float4*)wsm;
#pragma unroll
    for (int u = 0; u < 4; ++u) dst[u * 256 + tid] = src[u * 256 + tid];
  }
  int b = bh * 256 + tid;
  const float* xiT = xT + ((t == 1) ? 32768 : 0);  // branches 0,2 use vec1; 1 uses vec2
  const float* x3T = xT + 65536;                   // j-side is always vec3
  float x3r[64];
#pragma unroll
  for (int j = 0; j < 64; ++j) x3r[j] = x3T[j * 512 + b];   // coalesced
  __syncthreads();
  float acc = 0.f;
#pragma unroll 2
  for (int i = 0; i < 64; ++i) {
    float xi = xiT[i * 512 + b];                             // coalesced
    float s = 0.f;
    const float4* w4 = (const float4*)&wsm[i * 64];
#pragma unroll
    for (int q = 0; q < 16; ++q) {
      float4 w = w4[q];                                      // LDS broadcast
      s += w.x * x3r[q*4+0] + w.y * x3r[q*4+1] + w.z * x3r[q*4+2] + w.w * x3r[q*4+3];
    }
    acc += xi * s;
  }
  zsum[t * 32768 + o * 512 + b] = acc;
}

// ---------------- K2: per-branch h/o layers -> oT f32 [3][65][512], o3row bf16 [512][72]
// weights staged in LDS (kills uniform scalar-load chains)
__global__ void __launch_bounds__(256) k2_branch(
    const float* __restrict__ hw1, const float* __restrict__ hb1,
    const float* __restrict__ ow1, const float* __restrict__ ob1,
    const float* __restrict__ hw2, const float* __restrict__ hb2,
    const float* __restrict__ ow2, const float* __restrict__ ob2,
    const float* __restrict__ hw3, const float* __restrict__ hb3,
    const float* __restrict__ ow3, const float* __restrict__ ob3,
    const float* __restrict__ zb1, const float* __restrict__ zb2, const float* __restrict__ zb3,
    const float* __restrict__ xT, const float* __restrict__ zsum,
    float* __restrict__ oT, u16* __restrict__ o3row) {
  __shared__ float hws[4096];
  __shared__ float ows[4096];
  __shared__ float hbs[64], obs[64], zbs[64];
  __shared__ float gT[64][68];
  int t = blockIdx.x >> 3, bc = blockIdx.x & 7;   // 24 blocks
  int tid = threadIdx.x;
  int lane = tid & 63;
  int w = __builtin_amdgcn_readfirstlane((int)(tid >> 6));
  int b = bc * 64 + lane;
  const float* hw = (t==0)?hw1:((t==1)?hw2:hw3);
  const float* hb = (t==0)?hb1:((t==1)?hb2:hb3);
  const float* ow = (t==0)?ow1:((t==1)?ow2:ow3);
  const float* ob = (t==0)?ob1:((t==1)?ob2:ob3);
  const float* zb = (t==0)?zb1:((t==1)?zb2:zb3);
  {  // stage weights + biases, coalesced
    const float4* hs = (const float4*)hw;
    const float4* os = (const float4*)ow;
    float4* hd = (float4*)hws;
    float4* od = (float4*)ows;
#pragma unroll
    for (int u = 0; u < 4; ++u) { hd[u * 256 + tid] = hs[u * 256 + tid];
                                  od[u * 256 + tid] = os[u * 256 + tid]; }
    if (tid < 64) { hbs[tid] = hb[tid]; obs[tid] = ob[tid]; zbs[tid] = zb[tid]; }
  }
  const float* xtT = xT + t * 32768;
  float xr[64];
#pragma unroll
  for (int k = 0; k < 64; ++k) xr[k] = xtT[k * 512 + b];     // coalesced
  __syncthreads();
#pragma unroll
  for (int ii = 0; ii < 16; ii += 4) {
    float gv[4];
#pragma unroll
    for (int q = 0; q < 4; ++q) {
      int i = w * 16 + ii + q;
      float a = hbs[i];
      const float4* h4 = (const float4*)&hws[i * 64];
#pragma unroll
      for (int kq = 0; kq < 16; ++kq) {
        float4 h = h4[kq];
        a += h.x * xr[kq*4+0] + h.y * xr[kq*4+1] + h.z * xr[kq*4+2] + h.w * xr[kq*4+3];
      }
      float hv = fmaxf(a, 0.f);
      float z = zsum[t * 32768 + i * 512 + b] + zbs[i];
      float sg = 1.f / (1.f + __expf(-z));
      gv[q] = sg * hv;
    }
    *(float4*)&gT[lane][w * 16 + ii] = make_float4(gv[0], gv[1], gv[2], gv[3]);
  }
  __syncthreads();
  float gr[64];
#pragma unroll
  for (int k = 0; k < 64; k += 4) {
    float4 g4 = *(const float4*)&gT[lane][k];
    gr[k] = g4.x; gr[k+1] = g4.y; gr[k+2] = g4.z; gr[k+3] = g4.w;
  }
#pragma unroll
  for (int ii = 0; ii < 16; ++ii) {
    int oo = w * 16 + ii;
    float a = obs[oo];
    const float4* o4 = (const float4*)&ows[oo * 64];
#pragma unroll
    for (int kq = 0; kq < 16; ++kq) {
      float4 o = o4[kq];
      a += o.x * gr[kq*4+0] + o.y * gr[kq*4+1] + o.z * gr[kq*4+2] + o.w * gr[kq*4+3];
    }
    float ov = fmaxf(a, 0.f);
    oT[(t * 65 + oo) * 512 + b] = ov;
    if (t == 2) o3row[b * 72 + oo] = f2bf(ov);
  }
  if (w == 0) oT[(t * 65 + 64) * 512 + b] = 1.f;       // ones column
  if (t == 2 && w == 1) {
    uint4 ones = make_uint4(0x3F80u, 0u, 0u, 0u);      // bf16 1.0, then zero pad
    *(uint4*)&o3row[b * 72 + 64] = ones;
  }
}

// pack one staged W row-half into 8-chunk-permuted LDS row (stride 64 u16 = 128B).
// Permutation: logical 16B chunk lc lands at slot (lc + (row>>2) + 2*(row&3)) & 7
template<int S4>
__device__ __forceinline__ void pack_row(const uint4* qv, u16* bp, u16* vvp,
                                         int row, int hh) {
  u32 l[36];
#pragma unroll
  for (int r = 0; r < 9; ++r) {
    l[4*r+0] = qv[r].x; l[4*r+1] = qv[r].y; l[4*r+2] = qv[r].z; l[4*r+3] = qv[r].w;
  }
  int rp = (row >> 2) + 2 * (row & 3);
#pragma unroll
  for (int cl = 0; cl < 4; ++cl) {
    u32 p0 = pkbf(l[S4+8*cl+0], l[S4+8*cl+1]);
    u32 p1 = pkbf(l[S4+8*cl+2], l[S4+8*cl+3]);
    u32 p2 = pkbf(l[S4+8*cl+4], l[S4+8*cl+5]);
    u32 p3 = pkbf(l[S4+8*cl+6], l[S4+8*cl+7]);
    int pos = (hh * 4 + cl + rp) & 7;
    *(uint4*)(bp + (pos << 3)) = make_uint4(p0, p1, p2, p3);
  }
  if (hh) vvp[row] = (u16)(pkbf(l[S4+32], l[S4+32]) & 0xffffu);  // col 64
}

// ---------------- K4: main GEMM: C[b,o] = sum_f o123[b,f]*W1[o,f]
// 64x128 tile, grid 768 (3 blocks/CU, one clean round), A-fragments hoisted to
// registers (no A LDS), depth-2 reg prefetch, permuted Bs dbuf, single lgkm
// barrier per ij (global prefetch in flight across it).
__global__ void __launch_bounds__(256, 3) k4_gemm(
    const float* __restrict__ W, const u16* __restrict__ o3row,
    const float* __restrict__ oT, float* __restrict__ accum,
    float* __restrict__ pbuf, int mode) {
  __shared__ u16 Bs[2][128 * 64];      // permuted, 2x16 KB
  __shared__ u16 vvs[2][128];          // col-64 of each staged row
  __shared__ float o12sf[2][64];
  int bid = blockIdx.x;                // 768; 8 mb-sharers of a W slice on same XCD
  int xcd = bid & 7, slot = bid >> 3;  // slot 0..95
  int mb = slot & 7, ph = slot >> 3;   // ph 0..11
  int pair = ph * 8 + xcd;             // 0..95
  int sK = pair >> 1, nb = pair & 1;   // 48 split-K segments
  int mbase = mb * 64, nbase = nb * 128;
  int ij0 = (sK * IJ1) / NSK, ij1 = ((sK + 1) * IJ1) / NSK;
  int tid = threadIdx.x;
  int lane = tid & 63;
  int wid = __builtin_amdgcn_readfirstlane(tid >> 6);
  int lrow = lane & 15, lkg = lane >> 4;
  int rpos = lane >> 1, hh = lane & 1;   // 32 row-slots per wave, 2 threads/row

  v4f acc[8] = {};
  const uint4* Wq = (const uint4*)W;
  uint4 qa[9], qb[9];
  float aA = 0.f, aB = 0.f, bA = 0.f, bB = 0.f;

  auto loadW = [&](int ij, uint4* q) {
    int cc = (wid - ij) & 3;             // row rotation -> wave-uniform align phase
    int row = rpos * 4 + cc;
    long g = (long)(nbase + row) * F1 + (long)ij * 65;
    long u4 = (g >> 2) + (long)hh * 8;
#pragma unroll
    for (int r = 0; r < 9; ++r) q[r] = Wq[u4 + r];
  };
  auto loadO = [&](int ij, float& A, float& B) {
    if (tid < 64) {
      int i = ij / 65, j = ij - i * 65;
      A = oT[i * 512 + mbase + tid];
      B = oT[(65 + j) * 512 + mbase + tid];
    }
  };
  auto packCur = [&](int ij, int buf, const uint4* q, float pA, float pB) {
    int cc = (wid - ij) & 3;
    int row = rpos * 4 + cc;
    u16* bp = &Bs[buf][row << 6];
    if      (wid == 0) pack_row<0>(q, bp, &vvs[buf][0], row, hh);
    else if (wid == 1) pack_row<1>(q, bp, &vvs[buf][0], row, hh);
    else if (wid == 2) pack_row<2>(q, bp, &vvs[buf][0], row, hh);
    else               pack_row<3>(q, bp, &vvs[buf][0], row, hh);
    if (tid < 64) o12sf[buf][tid] = pA * pB;
  };

  loadW(ij0, qa); loadO(ij0, aA, aB);
  loadW(ij0 + 1, qb); loadO(ij0 + 1, bA, bB);

  // A fragments (ij-invariant) -> registers, direct from global
  v8bf af[4][2];
#pragma unroll
  for (int t2 = 0; t2 < 4; ++t2)
#pragma unroll
    for (int k2 = 0; k2 < 2; ++k2)
      af[t2][k2] = *(const v8bf*)&o3row[(mbase + t2 * 16 + lrow) * 72 + k2 * 32 + lkg * 8];

  // B-fragment u16-offsets (logical chunk lc = k2*4 + lkg), permuted
  int boff[2][2], vvr[2];
#pragma unroll
  for (int u2 = 0; u2 < 2; ++u2) {
    int rb = wid * 32 + u2 * 16 + lrow;
#pragma unroll
    for (int k2 = 0; k2 < 2; ++k2)
      boff[u2][k2] = (rb << 6) + (((k2 * 4 + lkg + (rb >> 2) + 2 * (rb & 3)) & 7) << 3);
    vvr[u2] = rb;
  }

  packCur(ij0, 0, qa, aA, aB);
  loadW(ij0 + 2, qa); loadO(ij0 + 2, aA, aB);
  asm volatile("s_waitcnt lgkmcnt(0)\n\ts_barrier" ::: "memory");

#pragma unroll 1
  for (int ij = ij0; ij < ij1; ++ij) {
    int cur = (ij - ij0) & 1;
    if (ij + 1 < ij1) {
      if (cur == 0) {
        packCur(ij + 1, 1, qb, bA, bB);
        if (ij + 3 < ij1) { loadW(ij + 3, qb); loadO(ij + 3, bA, bB); }
      } else {
        packCur(ij + 1, 0, qa, aA, aB);
        if (ij + 3 < ij1) { loadW(ij + 3, qa); loadO(ij + 3, aA, aB); }
      }
    }
    const u16* bs = Bs[cur];
    v8bf bf0[2], bf1[2];
#pragma unroll
    for (int k2 = 0; k2 < 2; ++k2) {
      bf0[k2] = *(const v8bf*)&bs[boff[0][k2]];
      bf1[k2] = *(const v8bf*)&bs[boff[1][k2]];
    }
    float vv0 = lof((u32)vvs[cur][vvr[0]]);
    float vv1 = lof((u32)vvs[cur][vvr[1]]);
    __builtin_amdgcn_s_setprio(1);
#pragma unroll
    for (int t2 = 0; t2 < 4; ++t2) {
      v4f P0 = {}, P1 = {};
      P0 = __builtin_amdgcn_mfma_f32_16x16x32_bf16(af[t2][0], bf0[0], P0, 0, 0, 0);
      P0 = __builtin_amdgcn_mfma_f32_16x16x32_bf16(af[t2][1], bf0[1], P0, 0, 0, 0);
      P1 = __builtin_amdgcn_mfma_f32_16x16x32_bf16(af[t2][0], bf1[0], P1, 0, 0, 0);
      P1 = __builtin_amdgcn_mfma_f32_16x16x32_bf16(af[t2][1], bf1[1], P1, 0, 0, 0);
      float4 sp = *(const float4*)&o12sf[cur][t2 * 16 + lkg * 4];
#pragma unroll
      for (int e = 0; e < 4; ++e) {
        float se = (e == 0) ? sp.x : (e == 1) ? sp.y : (e == 2) ? sp.z : sp.w;
        acc[t2 * 2 + 0][e] += se * (P0[e] + vv0);
        acc[t2 * 2 + 1][e] += se * (P1[e] + vv1);
      }
    }
    __builtin_amdgcn_s_setprio(0);
    asm volatile("s_waitcnt lgkmcnt(0)\n\ts_barrier" ::: "memory");
  }

  if (mode) {
    float* dst = pbuf + ((long)sK << 17);
#pragma unroll
    for (int t2 = 0; t2 < 4; ++t2) {
      int gb0 = mbase + t2 * 16 + lkg * 4;
#pragma unroll
      for (int u2 = 0; u2 < 2; ++u2) {
        int go = nbase + wid * 32 + u2 * 16 + lrow;
#pragma unroll
        for (int e = 0; e < 4; ++e)
          dst[(gb0 + e) * 256 + go] = acc[t2 * 2 + u2][e];
      }
    }
  } else {
#pragma unroll
    for (int t2 = 0; t2 < 4; ++t2) {
      int gb0 = mbase + t2 * 16 + lkg * 4;
#pragma unroll
      for (int u2 = 0; u2 < 2; ++u2) {
        int go = nbase + wid * 32 + u2 * 16 + lrow;
#pragma unroll
        for (int e = 0; e < 4; ++e)
          atomicAdd(&accum[(gb0 + e) * 256 + go], acc[t2 * 2 + u2][e]);
      }
    }
  }
}

// ---------------- K4R: reduce split-K partials, add enc1 bias, relu, TRANSPOSE
// pbuf [48][512][256] -> xrT [256][512]  (written into the accum slot; mode=1 only)
__global__ void __launch_bounds__(256) k4_reduce(const float* __restrict__ P,
    const float* __restrict__ e1b, float* __restrict__ xrT) {
  int g = blockIdx.x * 256 + threadIdx.x;       // float4 index, 32768 total
  const v4f* p4 = (const v4f*)P;
  v4f s = p4[g];
#pragma unroll 4
  for (int k = 1; k < NSK; ++k) s += p4[(k << 15) + g];
  int b = g >> 6, c0 = (g & 63) << 2;
#pragma unroll
  for (int e = 0; e < 4; ++e)
    xrT[(c0 + e) * 512 + b] = fmaxf(s[e] + e1b[c0 + e], 0.f);
}

// ---------------- K5V (mode=1): enc2 via transposed weights, vector loads.
__global__ void __launch_bounds__(256) k5v_enc2(const float* __restrict__ xrT,
    const float* __restrict__ oT, const float* __restrict__ w2T,
    const float* __restrict__ enc2b, float* __restrict__ outp) {
  __shared__ float xl[451 * 8 + 8];
  int b0 = blockIdx.x * 8;                      // 64 blocks
  int tid = threadIdx.x;
  for (int u = tid; u < 3608; u += 256) {
    int c = u >> 3, bi = u & 7;
    xl[u] = (c < 256) ? xrT[c * 512 + b0 + bi] : oT[(c - 256) * 512 + b0 + bi];
  }
  float a[8];
  float bv = enc2b[tid];
#pragma unroll
  for (int q = 0; q < 8; ++q) a[q] = bv;
  __syncthreads();
#pragma unroll 4
  for (int c = 0; c < 451; ++c) {
    float w = w2T[c * 256 + tid];               // coalesced vector load
    float4 x0 = *(const float4*)&xl[c * 8];     // LDS broadcast
    float4 x1 = *(const float4*)&xl[c * 8 + 4];
    a[0] += w * x0.x; a[1] += w * x0.y; a[2] += w * x0.z; a[3] += w * x0.w;
    a[4] += w * x1.x; a[5] += w * x1.y; a[6] += w * x1.z; a[7] += w * x1.w;
  }
#pragma unroll
  for (int q = 0; q < 8; ++q) outp[(b0 + q) * 256 + tid] = fmaxf(a[q], 0.f);
}

// ---------------- K5 (mode=0 fallback): old scalar path
__global__ void __launch_bounds__(256) k5_enc2(
    const float* __restrict__ xin, const float* __restrict__ oT,
    const float* __restrict__ enc1b, const float* __restrict__ w2,
    const float* __restrict__ enc2b, float* __restrict__ outp) {
  int bg = blockIdx.x >> 3, og = blockIdx.x & 7;   // 64 blocks
  int lane = threadIdx.x & 63;
  int w = __builtin_amdgcn_readfirstlane((int)(threadIdx.x >> 6));
  int b = bg * 64 + lane;
  int obase = og * 32 + w * 8;
  float a8[8];
#pragma unroll
  for (int q = 0; q < 8; ++q) a8[q] = enc2b[obase + q];
  for (int c = 0; c < 256; ++c) {
    float x = fmaxf(xin[b * 256 + c] + enc1b[c], 0.f);
#pragma unroll
    for (int q = 0; q < 8; ++q) a8[q] += w2[(obase + q) * 451 + c] * x;
  }
  for (int e = 0; e < 195; ++e) {
    float x = oT[e * 512 + b];
#pragma unroll
    for (int q = 0; q < 8; ++q) a8[q] += w2[(obase + q) * 451 + 256 + e] * x;
  }
#pragma unroll
  for (int q = 0; q < 8; ++q) outp[b * 256 + obase + q] = fmaxf(a8[q], 0.f);
}

extern "C" void kernel_launch(void* const* d_in, const int* in_sizes, int n_in,
                              void* d_out, int out_size, void* d_ws, size_t ws_size,
                              hipStream_t stream) {
  const float* vec1 = (const float*)d_in[0];
  const float* vec2 = (const float*)d_in[1];
  const float* vec3 = (const float*)d_in[2];
  const float* h1w = (const float*)d_in[3];  const float* h1b = (const float*)d_in[4];
  const float* z1w = (const float*)d_in[5];  const float* z1b = (const float*)d_in[6];
  const float* o1w = (const float*)d_in[7];  const float* o1b = (const float*)d_in[8];
  const float* h2w = (const float*)d_in[9];  const float* h2b = (const float*)d_in[10];
  const float* z2w = (const float*)d_in[11]; const float* z2b = (const float*)d_in[12];
  const float* o2w = (const float*)d_in[13]; const float* o2b = (const float*)d_in[14];
  const float* h3w = (const float*)d_in[15]; const float* h3b = (const float*)d_in[16];
  const float* z3w = (const float*)d_in[17]; const float* z3b = (const float*)d_in[18];
  const float* o3w = (const float*)d_in[19]; const float* o3b = (const float*)d_in[20];
  const float* e1w = (const float*)d_in[21]; const float* e1b = (const float*)d_in[22];
  const float* e2w = (const float*)d_in[23]; const float* e2b = (const float*)d_in[24];

  char* ws = (char*)d_ws;
  float* accum = (float*)(ws + 0);              // 524288 (mode1: xrT [256][512])
  float* oT    = (float*)(ws + 524288);         // 3*65*512*4 = 399360
  u16* o3row   = (u16*)  (ws + 923648);         // 512*72*2   = 73728
  float* xT    = (float*)(ws + 997376);         // 3*64*512*4 = 393216
  float* zsum  = (float*)(ws + 1390592);        // 3*64*512*4 = 393216
  float* w2T   = (float*)(ws + 1783808);        // 451*256*4 = 461824
  float* pbuf  = (float*)(ws + 2245632);        // 48*512*256*4 = 25165824
  size_t need = 2245632 + (size_t)NSK * 512 * 256 * 4;   // 27411456
  int mode = (ws_size >= need) ? 1 : 0;
  float* pArg = mode ? pbuf : accum;

  if (!mode) hipMemsetAsync(accum, 0, 524288, stream);

  hipLaunchKernelGGL(k0_transpose, dim3(384), dim3(256), 0, stream, vec1, vec2, vec3, xT);
  if (mode)
    hipLaunchKernelGGL(k3t_w2t, dim3(120), dim3(256), 0, stream, e2w, w2T);
  hipLaunchKernelGGL(k1_bilinear, dim3(384), dim3(256), 0, stream,
                     z1w, z2w, z3w, xT, zsum);
  hipLaunchKernelGGL(k2_branch, dim3(24), dim3(256), 0, stream,
                     h1w, h1b, o1w, o1b, h2w, h2b, o2w, o2b, h3w, h3b, o3w, o3b,
                     z1b, z2b, z3b, xT, zsum, oT, o3row);
  hipLaunchKernelGGL(k4_gemm, dim3(768), dim3(256), 0, stream, e1w, o3row, oT, accum,
                     pArg, mode);
  if (mode) {
    hipLaunchKernelGGL(k4_reduce, dim3(128), dim3(256), 0, stream, pbuf, e1b, accum);
    hipLaunchKernelGGL(k5v_enc2, dim3(64), dim3(256), 0, stream, accum, oT, w2T, e2b,
                       (float*)d_out);
  } else {
    hipLaunchKernelGGL(k5_enc2, dim3(64), dim3(256), 0, stream, accum, oT, e1b, e2w, e2b,
                       (float*)d_out);
  }
}

// Round 7
// 914.757 us; speedup vs baseline: 1.1881x; 1.1881x over previous
//
#include <hip/hip_runtime.h>
#include <hip/hip_bf16.h>
#include <stdint.h>

typedef unsigned short u16;
typedef unsigned int u32;

#define F1 274625   // 65^3
#define IJ1 4225    // 65^2
#define NSK 32      // split-K segments

typedef float v4f __attribute__((ext_vector_type(4)));
typedef float v4fa __attribute__((ext_vector_type(4), aligned(4)));  // align-4 float4
typedef __bf16 v8bf __attribute__((ext_vector_type(8)));

__device__ __forceinline__ u16 f2bf(float f) {
  union { float f; u32 u; } c; c.f = f;
  u32 r = (c.u >> 16) & 1u;
  return (u16)((c.u + 0x7fffu + r) >> 16);
}
__device__ __forceinline__ u32 pkbf(u32 a, u32 b) {
  union { float f; u32 u; } ca, cb; ca.u = a; cb.u = b;
  __hip_bfloat162 h = __float22bfloat162_rn(make_float2(ca.f, cb.f));
  union { __hip_bfloat162 h; u32 u; } c; c.h = h; return c.u;
}

// ---------------- K_PREP: blocks <384: transpose vecs -> xT; blocks >=384: w2 -> w2T
__global__ void __launch_bounds__(256) k_prep(const float* __restrict__ v1,
    const float* __restrict__ v2, const float* __restrict__ v3, float* __restrict__ xT,
    const float* __restrict__ w2, float* __restrict__ w2T) {
  if (blockIdx.x < 384) {
    int g = blockIdx.x * 256 + threadIdx.x;
    if (g >= 3 * 64 * 512) return;
    int t = g >> 15, r = g & 32767;
    int d = r >> 9, b = r & 511;
    const float* v = (t == 0) ? v1 : ((t == 1) ? v2 : v3);
    xT[g] = v[b * 64 + d];
  } else {
    __shared__ float t[32][33];
    int bb = blockIdx.x - 384;                       // 120 blocks
    int bx = bb & 7, by = bb >> 3;                   // 8 o-tiles x 15 c-tiles
    int tx = threadIdx.x & 31, ty = threadIdx.x >> 5;
    int c = by * 32 + tx;
#pragma unroll
    for (int r = 0; r < 32; r += 8) {
      int o = bx * 32 + ty + r;
      t[ty + r][tx] = (c < 451) ? w2[o * 451 + c] : 0.f;
    }
    __syncthreads();
#pragma unroll
    for (int r = 0; r < 32; r += 8) {
      int cc = by * 32 + ty + r;
      if (cc < 451) w2T[cc * 256 + bx * 32 + tx] = t[tx][ty + r];
    }
  }
}

// ---------------- K1: bilinear -> zsum [3][64][512] f32; weights staged in LDS
__global__ void __launch_bounds__(256) k1_bilinear(
    const float* __restrict__ zw1, const float* __restrict__ zw2, const float* __restrict__ zw3,
    const float* __restrict__ xT, float* __restrict__ zsum) {
  __shared__ float wsm[4096];
  int bid = blockIdx.x;                 // 384 = t*128 + o*2 + bh
  int bh = bid & 1, o = (bid >> 1) & 63, t = bid >> 7;
  int tid = threadIdx.x;
  const float* zw = (t == 0) ? zw1 : ((t == 1) ? zw2 : zw3);
  {
    const float4* src = (const float4*)(zw + o * 4096);
    float4* dst = (float4*)wsm;
#pragma unroll
    for (int u = 0; u < 4; ++u) dst[u * 256 + tid] = src[u * 256 + tid];
  }
  int b = bh * 256 + tid;
  const float* xiT = xT + ((t == 1) ? 32768 : 0);
  const float* x3T = xT + 65536;
  float x3r[64];
#pragma unroll
  for (int j = 0; j < 64; ++j) x3r[j] = x3T[j * 512 + b];
  __syncthreads();
  float acc = 0.f;
#pragma unroll 2
  for (int i = 0; i < 64; ++i) {
    float xi = xiT[i * 512 + b];
    float s = 0.f;
    const float4* w4 = (const float4*)&wsm[i * 64];
#pragma unroll
    for (int q = 0; q < 16; ++q) {
      float4 w = w4[q];
      s += w.x * x3r[q*4+0] + w.y * x3r[q*4+1] + w.z * x3r[q*4+2] + w.w * x3r[q*4+3];
    }
    acc += xi * s;
  }
  zsum[t * 32768 + o * 512 + b] = acc;
}

// ---------------- K2: per-branch h/o layers -> oT f32 [3][65][512], o3row bf16 [512][72]
__global__ void __launch_bounds__(256) k2_branch(
    const float* __restrict__ hw1, const float* __restrict__ hb1,
    const float* __restrict__ ow1, const float* __restrict__ ob1,
    const float* __restrict__ hw2, const float* __restrict__ hb2,
    const float* __restrict__ ow2, const float* __restrict__ ob2,
    const float* __restrict__ hw3, const float* __restrict__ hb3,
    const float* __restrict__ ow3, const float* __restrict__ ob3,
    const float* __restrict__ zb1, const float* __restrict__ zb2, const float* __restrict__ zb3,
    const float* __restrict__ xT, const float* __restrict__ zsum,
    float* __restrict__ oT, u16* __restrict__ o3row) {
  __shared__ float hws[4096];
  __shared__ float ows[4096];
  __shared__ float hbs[64], obs[64], zbs[64];
  __shared__ float gT[64][68];
  int t = blockIdx.x >> 3, bc = blockIdx.x & 7;   // 24 blocks
  int tid = threadIdx.x;
  int lane = tid & 63;
  int w = __builtin_amdgcn_readfirstlane((int)(tid >> 6));
  int b = bc * 64 + lane;
  const float* hw = (t==0)?hw1:((t==1)?hw2:hw3);
  const float* hb = (t==0)?hb1:((t==1)?hb2:hb3);
  const float* ow = (t==0)?ow1:((t==1)?ow2:ow3);
  const float* ob = (t==0)?ob1:((t==1)?ob2:ob3);
  const float* zb = (t==0)?zb1:((t==1)?zb2:zb3);
  {
    const float4* hs = (const float4*)hw;
    const float4* os = (const float4*)ow;
    float4* hd = (float4*)hws;
    float4* od = (float4*)ows;
#pragma unroll
    for (int u = 0; u < 4; ++u) { hd[u * 256 + tid] = hs[u * 256 + tid];
                                  od[u * 256 + tid] = os[u * 256 + tid]; }
    if (tid < 64) { hbs[tid] = hb[tid]; obs[tid] = ob[tid]; zbs[tid] = zb[tid]; }
  }
  const float* xtT = xT + t * 32768;
  float xr[64];
#pragma unroll
  for (int k = 0; k < 64; ++k) xr[k] = xtT[k * 512 + b];
  __syncthreads();
#pragma unroll
  for (int ii = 0; ii < 16; ii += 4) {
    float gv[4];
#pragma unroll
    for (int q = 0; q < 4; ++q) {
      int i = w * 16 + ii + q;
      float a = hbs[i];
      const float4* h4 = (const float4*)&hws[i * 64];
#pragma unroll
      for (int kq = 0; kq < 16; ++kq) {
        float4 h = h4[kq];
        a += h.x * xr[kq*4+0] + h.y * xr[kq*4+1] + h.z * xr[kq*4+2] + h.w * xr[kq*4+3];
      }
      float hv = fmaxf(a, 0.f);
      float z = zsum[t * 32768 + i * 512 + b] + zbs[i];
      float sg = 1.f / (1.f + __expf(-z));
      gv[q] = sg * hv;
    }
    *(float4*)&gT[lane][w * 16 + ii] = make_float4(gv[0], gv[1], gv[2], gv[3]);
  }
  __syncthreads();
  float gr[64];
#pragma unroll
  for (int k = 0; k < 64; k += 4) {
    float4 g4 = *(const float4*)&gT[lane][k];
    gr[k] = g4.x; gr[k+1] = g4.y; gr[k+2] = g4.z; gr[k+3] = g4.w;
  }
#pragma unroll
  for (int ii = 0; ii < 16; ++ii) {
    int oo = w * 16 + ii;
    float a = obs[oo];
    const float4* o4 = (const float4*)&ows[oo * 64];
#pragma unroll
    for (int kq = 0; kq < 16; ++kq) {
      float4 o = o4[kq];
      a += o.x * gr[kq*4+0] + o.y * gr[kq*4+1] + o.z * gr[kq*4+2] + o.w * gr[kq*4+3];
    }
    float ov = fmaxf(a, 0.f);
    oT[(t * 65 + oo) * 512 + b] = ov;
    if (t == 2) o3row[b * 72 + oo] = f2bf(ov);
  }
  if (w == 0) oT[(t * 65 + 64) * 512 + b] = 1.f;       // ones column
  if (t == 2 && w == 1) {
    uint4 ones = make_uint4(0x3F80u, 0u, 0u, 0u);      // bf16 1.0, then zero pad
    *(uint4*)&o3row[b * 72 + 64] = ones;
  }
}

// ---------------- K4: main GEMM, LDS-free. C[b,o] = sum_f o123[b,f]*W1[o,f]
// Each lane loads its MFMA B-fragment directly from W (8 consecutive f32,
// align-4 vector loads), converts f32->bf16 in-register. No LDS, no barriers;
// waves fully independent; 2-deep named ping-pong prefetch (pa/pb).
struct Pref { v4fa q[2][2][2]; float vv[2]; };

__global__ void __launch_bounds__(256, 2) k4_gemm(
    const float* __restrict__ W, const u16* __restrict__ o3row,
    const float* __restrict__ oT, float* __restrict__ accum,
    float* __restrict__ pbuf, int mode) {
  int bid = blockIdx.x;                // 512 = ph(8) x mb(8) x xcd(8)
  int xcd = bid & 7, mb = (bid >> 3) & 7, ph = bid >> 6;
  int pair = ph * 8 + xcd;             // 0..63; 8 mb-sharers of a slice on same XCD
  int sK = pair >> 1, nb = pair & 1;   // 32 split-K segments
  int mbase = mb * 64, nbase = nb * 128;
  int ij0 = (sK * IJ1) >> 5, ij1 = ((sK + 1) * IJ1) >> 5;
  int tid = threadIdx.x;
  int lane = tid & 63;
  int wid = __builtin_amdgcn_readfirstlane(tid >> 6);
  int lrow = lane & 15, lkg = lane >> 4;

  // A fragments (ij-invariant) from o3row global
  v8bf af[4][2];
#pragma unroll
  for (int t2 = 0; t2 < 4; ++t2)
#pragma unroll
    for (int k2 = 0; k2 < 2; ++k2)
      af[t2][k2] = *(const v8bf*)&o3row[(mbase + t2 * 16 + lrow) * 72 + k2 * 32 + lkg * 8];

  const float* Wr0 = W + (long)(nbase + wid * 32 +  0 + lrow) * F1;
  const float* Wr1 = W + (long)(nbase + wid * 32 + 16 + lrow) * F1;

  v4f acc[8] = {};

  auto loadP = [&](int ij, Pref& P) {
    int base = ij * 65 + lkg * 8;
#pragma unroll
    for (int k2 = 0; k2 < 2; ++k2) {
      P.q[0][k2][0] = *(const v4fa*)(Wr0 + base + k2 * 32);
      P.q[0][k2][1] = *(const v4fa*)(Wr0 + base + k2 * 32 + 4);
      P.q[1][k2][0] = *(const v4fa*)(Wr1 + base + k2 * 32);
      P.q[1][k2][1] = *(const v4fa*)(Wr1 + base + k2 * 32 + 4);
    }
    P.vv[0] = Wr0[ij * 65 + 64];
    P.vv[1] = Wr1[ij * 65 + 64];
  };

  auto step = [&](int ij, Pref& P, int ijn) {
    // f32 -> bf16 fragments (consumes P's loads)
    v8bf bf[2][2];
#pragma unroll
    for (int u2 = 0; u2 < 2; ++u2)
#pragma unroll
      for (int k2 = 0; k2 < 2; ++k2) {
        union { u32 u[4]; v8bf v; } cv;
        v4fa lo = P.q[u2][k2][0], hi = P.q[u2][k2][1];
        cv.u[0] = pkbf(__float_as_uint(lo.x), __float_as_uint(lo.y));
        cv.u[1] = pkbf(__float_as_uint(lo.z), __float_as_uint(lo.w));
        cv.u[2] = pkbf(__float_as_uint(hi.x), __float_as_uint(hi.y));
        cv.u[3] = pkbf(__float_as_uint(hi.z), __float_as_uint(hi.w));
        bf[u2][k2] = cv.v;
      }
    float vv0 = P.vv[0], vv1 = P.vv[1];
    loadP(ijn, P);                       // refill: ~2 iterations of latency cover
    int i = ij / 65, j = ij - i * 65;
    const float* o1p = oT + i * 512 + mbase + lkg * 4;
    const float* o2p = oT + (65 + j) * 512 + mbase + lkg * 4;
#pragma unroll
    for (int t2 = 0; t2 < 4; ++t2) {
      float4 o1r = *(const float4*)(o1p + t2 * 16);
      float4 o2r = *(const float4*)(o2p + t2 * 16);
      v4f P0 = {}, P1 = {};
      P0 = __builtin_amdgcn_mfma_f32_16x16x32_bf16(af[t2][0], bf[0][0], P0, 0, 0, 0);
      P0 = __builtin_amdgcn_mfma_f32_16x16x32_bf16(af[t2][1], bf[0][1], P0, 0, 0, 0);
      P1 = __builtin_amdgcn_mfma_f32_16x16x32_bf16(af[t2][0], bf[1][0], P1, 0, 0, 0);
      P1 = __builtin_amdgcn_mfma_f32_16x16x32_bf16(af[t2][1], bf[1][1], P1, 0, 0, 0);
      float sp0 = o1r.x * o2r.x, sp1 = o1r.y * o2r.y;
      float sp2 = o1r.z * o2r.z, sp3 = o1r.w * o2r.w;
      acc[t2 * 2 + 0][0] += sp0 * (P0[0] + vv0);
      acc[t2 * 2 + 0][1] += sp1 * (P0[1] + vv0);
      acc[t2 * 2 + 0][2] += sp2 * (P0[2] + vv0);
      acc[t2 * 2 + 0][3] += sp3 * (P0[3] + vv0);
      acc[t2 * 2 + 1][0] += sp0 * (P1[0] + vv1);
      acc[t2 * 2 + 1][1] += sp1 * (P1[1] + vv1);
      acc[t2 * 2 + 1][2] += sp2 * (P1[2] + vv1);
      acc[t2 * 2 + 1][3] += sp3 * (P1[3] + vv1);
    }
  };

  Pref pa, pb;
  loadP(ij0, pa);
  loadP(ij0 + 1, pb);
  int ij = ij0;
  for (; ij + 1 < ij1; ij += 2) {
    step(ij,     pa, (ij + 2 < ij1) ? ij + 2 : ij1 - 1);
    step(ij + 1, pb, (ij + 3 < ij1) ? ij + 3 : ij1 - 1);
  }
  if (ij < ij1) step(ij, pa, ij1 - 1);

  if (mode) {
    float* dst = pbuf + ((long)sK << 17);
#pragma unroll
    for (int t2 = 0; t2 < 4; ++t2) {
      int gb0 = mbase + t2 * 16 + lkg * 4;
#pragma unroll
      for (int u2 = 0; u2 < 2; ++u2) {
        int go = nbase + wid * 32 + u2 * 16 + lrow;
#pragma unroll
        for (int e = 0; e < 4; ++e)
          dst[(gb0 + e) * 256 + go] = acc[t2 * 2 + u2][e];
      }
    }
  } else {
#pragma unroll
    for (int t2 = 0; t2 < 4; ++t2) {
      int gb0 = mbase + t2 * 16 + lkg * 4;
#pragma unroll
      for (int u2 = 0; u2 < 2; ++u2) {
        int go = nbase + wid * 32 + u2 * 16 + lrow;
#pragma unroll
        for (int e = 0; e < 4; ++e)
          atomicAdd(&accum[(gb0 + e) * 256 + go], acc[t2 * 2 + u2][e]);
      }
    }
  }
}

// ---------------- K5V (mode=1): fused split-K reduce + bias/relu + enc2.
// Per block: reduce pbuf slice for its 8 batch rows in-register, stage x in LDS,
// then coalesced w2T dot.
__global__ void __launch_bounds__(256) k5v_enc2(const float* __restrict__ pbuf,
    const float* __restrict__ oT, const float* __restrict__ w2T,
    const float* __restrict__ e1b, const float* __restrict__ enc2b,
    float* __restrict__ outp) {
  __shared__ float xl[451 * 8 + 8];
  int b0 = blockIdx.x * 8;                      // 64 blocks
  int tid = threadIdx.x;
  float s[8] = {0.f, 0.f, 0.f, 0.f, 0.f, 0.f, 0.f, 0.f};
  for (int k = 0; k < NSK; ++k) {
    const float* pk = pbuf + ((long)k << 17) + b0 * 256 + tid;
#pragma unroll
    for (int r = 0; r < 8; ++r) s[r] += pk[r * 256];
  }
  float bias = e1b[tid];
#pragma unroll
  for (int r = 0; r < 8; ++r) xl[tid * 8 + r] = fmaxf(s[r] + bias, 0.f);
  for (int u = tid; u < 195 * 8; u += 256) {
    int c = u >> 3, bi = u & 7;
    xl[(256 + c) * 8 + bi] = oT[c * 512 + b0 + bi];
  }
  float a[8];
  float bv = enc2b[tid];
#pragma unroll
  for (int q = 0; q < 8; ++q) a[q] = bv;
  __syncthreads();
#pragma unroll 4
  for (int c = 0; c < 451; ++c) {
    float w = w2T[c * 256 + tid];               // coalesced
    float4 x0 = *(const float4*)&xl[c * 8];     // LDS broadcast
    float4 x1 = *(const float4*)&xl[c * 8 + 4];
    a[0] += w * x0.x; a[1] += w * x0.y; a[2] += w * x0.z; a[3] += w * x0.w;
    a[4] += w * x1.x; a[5] += w * x1.y; a[6] += w * x1.z; a[7] += w * x1.w;
  }
#pragma unroll
  for (int q = 0; q < 8; ++q) outp[(b0 + q) * 256 + tid] = fmaxf(a[q], 0.f);
}

// ---------------- K5 (mode=0 fallback): scalar path
__global__ void __launch_bounds__(256) k5_enc2(
    const float* __restrict__ xin, const float* __restrict__ oT,
    const float* __restrict__ enc1b, const float* __restrict__ w2,
    const float* __restrict__ enc2b, float* __restrict__ outp) {
  int bg = blockIdx.x >> 3, og = blockIdx.x & 7;   // 64 blocks
  int lane = threadIdx.x & 63;
  int w = __builtin_amdgcn_readfirstlane((int)(threadIdx.x >> 6));
  int b = bg * 64 + lane;
  int obase = og * 32 + w * 8;
  float a8[8];
#pragma unroll
  for (int q = 0; q < 8; ++q) a8[q] = enc2b[obase + q];
  for (int c = 0; c < 256; ++c) {
    float x = fmaxf(xin[b * 256 + c] + enc1b[c], 0.f);
#pragma unroll
    for (int q = 0; q < 8; ++q) a8[q] += w2[(obase + q) * 451 + c] * x;
  }
  for (int e = 0; e < 195; ++e) {
    float x = oT[e * 512 + b];
#pragma unroll
    for (int q = 0; q < 8; ++q) a8[q] += w2[(obase + q) * 451 + 256 + e] * x;
  }
#pragma unroll
  for (int q = 0; q < 8; ++q) outp[b * 256 + obase + q] = fmaxf(a8[q], 0.f);
}

extern "C" void kernel_launch(void* const* d_in, const int* in_sizes, int n_in,
                              void* d_out, int out_size, void* d_ws, size_t ws_size,
                              hipStream_t stream) {
  const float* vec1 = (const float*)d_in[0];
  const float* vec2 = (const float*)d_in[1];
  const float* vec3 = (const float*)d_in[2];
  const float* h1w = (const float*)d_in[3];  const float* h1b = (const float*)d_in[4];
  const float* z1w = (const float*)d_in[5];  const float* z1b = (const float*)d_in[6];
  const float* o1w = (const float*)d_in[7];  const float* o1b = (const float*)d_in[8];
  const float* h2w = (const float*)d_in[9];  const float* h2b = (const float*)d_in[10];
  const float* z2w = (const float*)d_in[11]; const float* z2b = (const float*)d_in[12];
  const float* o2w = (const float*)d_in[13]; const float* o2b = (const float*)d_in[14];
  const float* h3w = (const float*)d_in[15]; const float* h3b = (const float*)d_in[16];
  const float* z3w = (const float*)d_in[17]; const float* z3b = (const float*)d_in[18];
  const float* o3w = (const float*)d_in[19]; const float* o3b = (const float*)d_in[20];
  const float* e1w = (const float*)d_in[21]; const float* e1b = (const float*)d_in[22];
  const float* e2w = (const float*)d_in[23]; const float* e2b = (const float*)d_in[24];

  char* ws = (char*)d_ws;
  float* accum = (float*)(ws + 0);              // 524288 (mode0 only)
  float* oT    = (float*)(ws + 524288);         // 3*65*512*4 = 399360
  u16* o3row   = (u16*)  (ws + 923648);         // 512*72*2   = 73728
  float* xT    = (float*)(ws + 997376);         // 3*64*512*4 = 393216
  float* zsum  = (float*)(ws + 1390592);        // 3*64*512*4 = 393216
  float* w2T   = (float*)(ws + 1783808);        // 451*256*4 = 461824
  float* pbuf  = (float*)(ws + 2245632);        // 32*512*256*4 = 16777216
  size_t need = 2245632 + (size_t)NSK * 512 * 256 * 4;   // 19022848
  int mode = (ws_size >= need) ? 1 : 0;
  float* pArg = mode ? pbuf : accum;

  if (!mode) hipMemsetAsync(accum, 0, 524288, stream);

  hipLaunchKernelGGL(k_prep, dim3(mode ? 504 : 384), dim3(256), 0, stream,
                     vec1, vec2, vec3, xT, e2w, w2T);
  hipLaunchKernelGGL(k1_bilinear, dim3(384), dim3(256), 0, stream,
                     z1w, z2w, z3w, xT, zsum);
  hipLaunchKernelGGL(k2_branch, dim3(24), dim3(256), 0, stream,
                     h1w, h1b, o1w, o1b, h2w, h2b, o2w, o2b, h3w, h3b, o3w, o3b,
                     z1b, z2b, z3b, xT, zsum, oT, o3row);
  hipLaunchKernelGGL(k4_gemm, dim3(512), dim3(256), 0, stream, e1w, o3row, oT, accum,
                     pArg, mode);
  if (mode) {
    hipLaunchKernelGGL(k5v_enc2, dim3(64), dim3(256), 0, stream, pbuf, oT, w2T,
                       e1b, e2b, (float*)d_out);
  } else {
    hipLaunchKernelGGL(k5_enc2, dim3(64), dim3(256), 0, stream, accum, oT, e1b, e2w, e2b,
                       (float*)d_out);
  }
}